// Round 3
// baseline (325.230 us; speedup 1.0000x reference)
//
#include <hip/hip_runtime.h>

#define BATCH 4
#define CCH 128
#define NSP 4096
#define NGRP 8
#define GROUP_ELEMS 65536   // 16 ch * 4096
// ATT_SCALE * log2(e): folded into q at qk_gemm so softmax is exp2(s)
#define QSCALE 0.12751744f
#define EPS_GN 1e-5f

typedef short s8b __attribute__((ext_vector_type(8)));
typedef float f32x4 __attribute__((ext_vector_type(4)));

static __device__ __forceinline__ short f2bf(float f) {
  union { float f; unsigned u; } v; v.f = f;
  unsigned r = (v.u + 0x7FFFu + ((v.u >> 16) & 1u)) >> 16;
  return (short)r;
}

static __device__ __forceinline__ float fexp2(float x) {
#if __has_builtin(__builtin_amdgcn_exp2f)
  return __builtin_amdgcn_exp2f(x);
#else
  return exp2f(x);
#endif
}

static __device__ __forceinline__ f32x4 mfma16(s8b a, s8b b, f32x4 c) {
  return __builtin_amdgcn_mfma_f32_16x16x32_bf16(a, b, c, 0, 0, 0);
}

// ---------------- GroupNorm pass 1: per-(b,g,chunk) partial sum/sumsq ----------------
__global__ void gn_stats(const float* __restrict__ x, float* __restrict__ part) {
  int bx = blockIdx.x;            // 256 = bg(32) * chunk(8)
  int ch = bx & 7, bg = bx >> 3;
  const float* base = x + (size_t)bg * GROUP_ELEMS + (size_t)ch * 8192;
  int t = threadIdx.x;
  float s = 0.f, ss = 0.f;
  #pragma unroll
  for (int i = 0; i < 8; ++i) {
    float4 v = *(const float4*)(base + i * 1024 + t * 4);
    s  += v.x + v.y + v.z + v.w;
    ss += v.x * v.x + v.y * v.y + v.z * v.z + v.w * v.w;
  }
  #pragma unroll
  for (int off = 1; off < 64; off <<= 1) {
    s  += __shfl_xor(s, off);
    ss += __shfl_xor(ss, off);
  }
  __shared__ float red[8];
  int w = t >> 6;
  if ((t & 63) == 0) { red[w * 2] = s; red[w * 2 + 1] = ss; }
  __syncthreads();
  if (t == 0) {
    part[bx * 2]     = red[0] + red[2] + red[4] + red[6];
    part[bx * 2 + 1] = red[1] + red[3] + red[5] + red[7];
  }
}

// ---------------- GroupNorm pass 2: reduce partials, normalize, write xn (b,n,c) bf16 ----------------
__global__ void gn_apply(const float* __restrict__ x, const float* __restrict__ gw,
                         const float* __restrict__ gb, const float* __restrict__ part,
                         short* __restrict__ xn) {
  int bx = blockIdx.x;            // 256 = b(4) g(8) ns(8)
  int ns = bx & 7, g = (bx >> 3) & 7, b = bx >> 6;
  int bg = b * NGRP + g;
  float s = 0.f, ss = 0.f;
  #pragma unroll
  for (int j = 0; j < 8; ++j) {
    s  += part[(bg * 8 + j) * 2];
    ss += part[(bg * 8 + j) * 2 + 1];
  }
  float mean = s * (1.f / GROUP_ELEMS);
  float var  = ss * (1.f / GROUP_ELEMS) - mean * mean;
  float inv  = rsqrtf(var + EPS_GN);
  int t = threadIdx.x;
  int cl = t & 15, n4 = t >> 4;
  int c = g * 16 + cl;
  float ga = gw[c] * inv;
  float be = gb[c] - mean * ga;
  const float* xr = x + (size_t)(b * CCH + c) * NSP;
  short* xo = xn + (size_t)b * NSP * CCH + c;
  #pragma unroll
  for (int i = 0; i < 8; ++i) {
    int n = ns * 512 + i * 64 + n4 * 4;
    float4 v = *(const float4*)(xr + n);
    xo[(size_t)(n + 0) * CCH] = f2bf(v.x * ga + be);
    xo[(size_t)(n + 1) * CCH] = f2bf(v.y * ga + be);
    xo[(size_t)(n + 2) * CCH] = f2bf(v.z * ga + be);
    xo[(size_t)(n + 3) * CCH] = f2bf(v.w * ga + be);
  }
}

// ---------------- QKV (q,k part): D[n][o]; q pre-scaled by QSCALE ----------------
__global__ void qk_gemm(const short* __restrict__ xn, const float* __restrict__ Wqkv,
                        const float* __restrict__ bias, short* __restrict__ q,
                        short* __restrict__ k) {
  int bx = blockIdx.x;            // 1024 = b(4) nt(64) ot(4)
  int ot = bx & 3, nt = (bx >> 2) & 63, b = bx >> 8;
  __shared__ short Xl[64][136];
  __shared__ short Wl[64][136];
  int t = threadIdx.x;
  for (int idx = t; idx < 64 * 16; idx += 256) {
    int row = idx >> 4, c8 = idx & 15;
    *(s8b*)&Xl[row][c8 * 8] =
        *(const s8b*)(xn + ((size_t)(b * NSP + nt * 64 + row)) * CCH + c8 * 8);
  }
  for (int idx = t; idx < 64 * 16; idx += 256) {
    int row = idx >> 4, c8 = idx & 15;
    const float* src = Wqkv + (size_t)(ot * 64 + row) * CCH + c8 * 8;
    s8b wv;
    #pragma unroll
    for (int j = 0; j < 8; ++j) wv[j] = f2bf(src[j]);
    *(s8b*)&Wl[row][c8 * 8] = wv;
  }
  __syncthreads();
  int lane = t & 63, w = t >> 6, l15 = lane & 15, quad = lane >> 4;
  s8b a[4];
  #pragma unroll
  for (int kc = 0; kc < 4; ++kc) a[kc] = *(const s8b*)&Xl[w * 16 + l15][kc * 32 + quad * 8];
  #pragma unroll
  for (int o4 = 0; o4 < 4; ++o4) {
    f32x4 acc = {0.f, 0.f, 0.f, 0.f};
    #pragma unroll
    for (int kc = 0; kc < 4; ++kc) {
      s8b bw = *(const s8b*)&Wl[o4 * 16 + l15][kc * 32 + quad * 8];
      acc = mfma16(a[kc], bw, acc);
    }
    int obase = ot * 64 + o4 * 16;
    short* dst = (obase < 128) ? q : k;
    float mulf = (obase < 128) ? QSCALE : 1.0f;
    int oc = obase - ((obase < 128) ? 0 : 128) + l15;
    float bs = bias[obase + l15];
    #pragma unroll
    for (int r = 0; r < 4; ++r) {
      int n = nt * 64 + w * 16 + quad * 4 + r;
      dst[((size_t)(b * NSP + n)) * CCH + oc] = f2bf((acc[r] + bs) * mulf);
    }
  }
}

// ---------------- QKV (v part): D[o][n], writes v transposed (b,c,n) bf16 ----------------
__global__ void v_gemm(const short* __restrict__ xn, const float* __restrict__ Wqkv,
                       const float* __restrict__ bias, short* __restrict__ vt) {
  int bx = blockIdx.x;            // 256 = b(4) nt(32) ot(2)
  int ot = bx & 1, nt = (bx >> 1) & 31, b = bx >> 6;
  __shared__ short Xl[128][136];
  __shared__ short Wl[64][136];
  int t = threadIdx.x;
  for (int idx = t; idx < 128 * 16; idx += 256) {
    int row = idx >> 4, c8 = idx & 15;
    *(s8b*)&Xl[row][c8 * 8] =
        *(const s8b*)(xn + ((size_t)(b * NSP + nt * 128 + row)) * CCH + c8 * 8);
  }
  for (int idx = t; idx < 64 * 16; idx += 256) {
    int row = idx >> 4, c8 = idx & 15;
    const float* src = Wqkv + (size_t)(256 + ot * 64 + row) * CCH + c8 * 8;
    s8b wv;
    #pragma unroll
    for (int j = 0; j < 8; ++j) wv[j] = f2bf(src[j]);
    *(s8b*)&Wl[row][c8 * 8] = wv;
  }
  __syncthreads();
  int lane = t & 63, w = t >> 6, l15 = lane & 15, quad = lane >> 4;
  s8b a[4];
  #pragma unroll
  for (int kc = 0; kc < 4; ++kc) a[kc] = *(const s8b*)&Wl[w * 16 + l15][kc * 32 + quad * 8];
  float bs[4];
  #pragma unroll
  for (int r = 0; r < 4; ++r) bs[r] = bias[256 + ot * 64 + w * 16 + quad * 4 + r];
  #pragma unroll
  for (int ntile = 0; ntile < 8; ++ntile) {
    f32x4 acc = {0.f, 0.f, 0.f, 0.f};
    #pragma unroll
    for (int kc = 0; kc < 4; ++kc) {
      s8b bx2 = *(const s8b*)&Xl[ntile * 16 + l15][kc * 32 + quad * 8];
      acc = mfma16(a[kc], bx2, acc);
    }
    #pragma unroll
    for (int r = 0; r < 4; ++r) {
      int og = ot * 64 + w * 16 + quad * 4 + r;       // v channel
      int n = nt * 128 + ntile * 16 + l15;
      vt[((size_t)(b * CCH + og)) * NSP + n] = f2bf(acc[r] + bs[r]);
    }
  }
}

// ---------------- Flash attention v3 ----------------
// 512 blocks (XCD-swizzled: b=(bx>>1)&3), 32-row q-tiles; 8 waves = 4 KV-streams
// x 2 row-halves; 16-row waves, VGPR<=128 forced => 2 blocks/CU (16 waves/CU).
// Fixed-zero softmax max (scores bounded ~|12|): p=exp2(s) (q pre-scaled by
// QSCALE), l deferred to one post-loop butterfly, partials merged by PLAIN SUM.
__global__ __launch_bounds__(512, 4) void flash(const short* __restrict__ q,
                                                const short* __restrict__ k,
                                                const short* __restrict__ vt,
                                                short* __restrict__ ao) {
  int bx = blockIdx.x;                    // 512 = qhi(6) b(2) qlo(1)
  int b = (bx >> 1) & 3;                  // same b for both blocks on an XCD
  int qt = ((bx >> 3) << 1) | (bx & 1);   // 0..127: 32-row q-tile
  __shared__ short Pl[8][16 * 74];        // per-wave P transpose, pitch 74
  __shared__ float Obuf[32 * 132];
  __shared__ float Lbuf[32];
  int t = threadIdx.x;
  int lane = t & 63, w = t >> 6;          // w in [0,8)
  int st = w >> 1, ph = w & 1;            // kv stream / row half
  int l15 = lane & 15, quad = lane >> 4;

  s8b aq[4];
  {
    const short* qp =
        q + ((size_t)(b * NSP + qt * 32 + ph * 16 + l15)) * CCH + quad * 8;
    #pragma unroll
    for (int kc = 0; kc < 4; ++kc) aq[kc] = *(const s8b*)(qp + kc * 32);
  }
  f32x4 O[8];
  #pragma unroll
  for (int cg = 0; cg < 8; ++cg) O[cg] = (f32x4){0.f, 0.f, 0.f, 0.f};
  float l4[4] = {0.f, 0.f, 0.f, 0.f};
  const short* kbase = k + (size_t)b * NSP * CCH;
  const short* vbase = vt + (size_t)b * CCH * NSP;
  short* pw = &Pl[w][0];

  for (int i = 0; i < 16; ++i) {
    int ktv = (st + 4 * i) * 64;
    // ---- S = Q K^T : 16 q-rows x 64 keys ----
    f32x4 s[4];
    #pragma unroll
    for (int g2 = 0; g2 < 4; ++g2) {
      const short* kp = kbase + (size_t)(ktv + g2 * 16 + l15) * CCH + quad * 8;
      s8b b0 = *(const s8b*)kp;
      s8b b1 = *(const s8b*)(kp + 32);
      s8b b2 = *(const s8b*)(kp + 64);
      s8b b3 = *(const s8b*)(kp + 96);
      f32x4 acc = {0.f, 0.f, 0.f, 0.f};
      acc = mfma16(aq[0], b0, acc);
      acc = mfma16(aq[1], b1, acc);
      acc = mfma16(aq[2], b2, acc);
      acc = mfma16(aq[3], b3, acc);
      s[g2] = acc;
    }
    // ---- V fragments (issue early; compiler may sink under reg cap) ----
    s8b vf[8][2];
    #pragma unroll
    for (int cg = 0; cg < 8; ++cg) {
      const short* vp = vbase + (size_t)(cg * 16 + l15) * NSP + ktv + quad * 8;
      vf[cg][0] = *(const s8b*)vp;
      vf[cg][1] = *(const s8b*)(vp + 32);
    }
    // ---- p = exp2(s); accumulate per-lane l; pack to LDS (round-half-up) ----
    #pragma unroll
    for (int g2 = 0; g2 < 4; ++g2) {
      #pragma unroll
      for (int r = 0; r < 4; ++r) {
        float p = fexp2(s[g2][r]);
        l4[r] += p;
        unsigned u; __builtin_memcpy(&u, &p, 4);
        pw[(quad * 4 + r) * 74 + g2 * 16 + l15] = (short)((u + 0x8000u) >> 16);
      }
    }
    // ---- P A-fragments (per-wave LDS, no barrier) ----
    s8b pf0 = *(const s8b*)&pw[l15 * 74 + quad * 8];
    s8b pf1 = *(const s8b*)&pw[l15 * 74 + 32 + quad * 8];
    // ---- O += P V ----
    #pragma unroll
    for (int cg = 0; cg < 8; ++cg) {
      O[cg] = mfma16(pf0, vf[cg][0], O[cg]);
      O[cg] = mfma16(pf1, vf[cg][1], O[cg]);
    }
  }
  // ---- one deferred l reduction (16 lanes within quad) ----
  #pragma unroll
  for (int off = 1; off < 16; off <<= 1)
    #pragma unroll
    for (int r = 0; r < 4; ++r) l4[r] += __shfl_xor(l4[r], off);

  // ---- merge 4 streams: plain sums (fixed-max softmax partials) ----
  for (int p = 0; p < 4; ++p) {
    if (st == p) {
      #pragma unroll
      for (int r = 0; r < 4; ++r) {
        int row = ph * 16 + quad * 4 + r;
        if (p == 0) {
          if (l15 == 0) Lbuf[row] = l4[r];
          #pragma unroll
          for (int cg = 0; cg < 8; ++cg)
            Obuf[row * 132 + cg * 16 + l15] = O[cg][r];
        } else {
          if (l15 == 0) Lbuf[row] += l4[r];
          #pragma unroll
          for (int cg = 0; cg < 8; ++cg)
            Obuf[row * 132 + cg * 16 + l15] += O[cg][r];
        }
      }
    }
    __syncthreads();
  }
  // ---- normalize + write ao (b,n,c) bf16 ----
  {
    int row = t >> 4, c0 = (t & 15) * 8;
    float linv = 1.f / Lbuf[row];
    short* dst = ao + ((size_t)(b * NSP + qt * 32 + row)) * CCH + c0;
    #pragma unroll
    for (int j = 0; j < 8; ++j) dst[j] = f2bf(Obuf[row * 132 + c0 + j] * linv);
  }
}

// ---------------- proj + bias + residual: out (b,c,n) fp32 ----------------
__global__ void proj_gemm(const short* __restrict__ ao, const float* __restrict__ Wp,
                          const float* __restrict__ pbias, const float* __restrict__ x,
                          float* __restrict__ out) {
  int bx = blockIdx.x;            // 256 = b(4) nt(64)
  int nt = bx & 63, b = bx >> 6;
  __shared__ short Wl[128][136];
  int t = threadIdx.x;
  for (int idx = t; idx < 128 * 16; idx += 256) {
    int row = idx >> 4, c8 = idx & 15;
    const float* src = Wp + (size_t)row * CCH + c8 * 8;
    s8b wv;
    #pragma unroll
    for (int j = 0; j < 8; ++j) wv[j] = f2bf(src[j]);
    *(s8b*)&Wl[row][c8 * 8] = wv;
  }
  __syncthreads();
  int lane = t & 63, w = t >> 6, l15 = lane & 15, quad = lane >> 4;
  s8b bfr[4];
  const short* ap = ao + ((size_t)(b * NSP + nt * 64 + w * 16 + l15)) * CCH + quad * 8;
  #pragma unroll
  for (int kc = 0; kc < 4; ++kc) bfr[kc] = *(const s8b*)(ap + kc * 32);
  #pragma unroll
  for (int cg = 0; cg < 8; ++cg) {
    f32x4 acc = {0.f, 0.f, 0.f, 0.f};
    #pragma unroll
    for (int kc = 0; kc < 4; ++kc) {
      s8b aw = *(const s8b*)&Wl[cg * 16 + l15][kc * 32 + quad * 8];
      acc = mfma16(aw, bfr[kc], acc);
    }
    #pragma unroll
    for (int r = 0; r < 4; ++r) {
      int co = cg * 16 + quad * 4 + r;
      int n = nt * 64 + w * 16 + l15;
      size_t off = ((size_t)(b * CCH + co)) * NSP + n;
      out[off] = x[off] + acc[r] + pbias[co];
    }
  }
}

extern "C" void kernel_launch(void* const* d_in, const int* in_sizes, int n_in,
                              void* d_out, int out_size, void* d_ws, size_t ws_size,
                              hipStream_t stream) {
  (void)in_sizes; (void)n_in; (void)out_size; (void)ws_size;
  const float* x    = (const float*)d_in[0];
  const float* gw   = (const float*)d_in[1];
  const float* gb   = (const float*)d_in[2];
  const float* Wqkv = (const float*)d_in[3];
  const float* bqkv = (const float*)d_in[4];
  const float* Wp   = (const float*)d_in[5];
  const float* bp   = (const float*)d_in[6];
  float* out = (float*)d_out;
  char* ws = (char*)d_ws;
  float* part = (float*)ws;                       // 512 floats
  short* xn = (short*)(ws + 4096);
  short* q  = (short*)(ws + 4096 + 1ull * 4194304);
  short* k  = (short*)(ws + 4096 + 2ull * 4194304);
  short* vt = (short*)(ws + 4096 + 3ull * 4194304);
  short* ao = (short*)(ws + 4096 + 4ull * 4194304);

  gn_stats<<<256, 256, 0, stream>>>(x, part);
  gn_apply<<<256, 256, 0, stream>>>(x, gw, gb, part, xn);
  qk_gemm<<<1024, 256, 0, stream>>>(xn, Wqkv, bqkv, q, k);
  v_gemm<<<256, 256, 0, stream>>>(xn, Wqkv, bqkv, vt);
  flash<<<512, 512, 0, stream>>>(q, k, vt, ao);
  proj_gemm<<<256, 256, 0, stream>>>(ao, Wp, bp, x, out);
}

// Round 5
// 149.759 us; speedup vs baseline: 2.1717x; 2.1717x over previous
//
#include <hip/hip_runtime.h>

#define BATCH 4
#define CCH 128
#define NSP 4096
#define NGRP 8
#define GROUP_ELEMS 65536   // 16 ch * 4096
// ATT_SCALE * log2(e): folded into q at qk_gemm so softmax is exp2(s)
#define QSCALE 0.12751744f
#define EPS_GN 1e-5f
#define OPSTRIDE 2097152    // 4*4096*128 shorts per kh partial
#define LPSTRIDE 16384      // 4*4096 floats per kh partial

typedef short s8b __attribute__((ext_vector_type(8)));
typedef float f32x4 __attribute__((ext_vector_type(4)));

static __device__ __forceinline__ short f2bf(float f) {
  union { float f; unsigned u; } v; v.f = f;
  unsigned r = (v.u + 0x7FFFu + ((v.u >> 16) & 1u)) >> 16;
  return (short)r;
}

static __device__ __forceinline__ float bf2f(short s) {
  unsigned u = ((unsigned)(unsigned short)s) << 16;
  float f; __builtin_memcpy(&f, &u, 4); return f;
}

static __device__ __forceinline__ float fexp2(float x) {
#if __has_builtin(__builtin_amdgcn_exp2f)
  return __builtin_amdgcn_exp2f(x);
#else
  return exp2f(x);
#endif
}

static __device__ __forceinline__ f32x4 mfma16(s8b a, s8b b, f32x4 c) {
  return __builtin_amdgcn_mfma_f32_16x16x32_bf16(a, b, c, 0, 0, 0);
}

// async 16B global->LDS DMA; dest = wave-uniform base + lane*16
static __device__ __forceinline__ void async16(const void* g, void* l) {
  __builtin_amdgcn_global_load_lds(
      (const __attribute__((address_space(1))) void*)g,
      (__attribute__((address_space(3))) void*)l, 16, 0, 0);
}

// ---------------- GroupNorm pass 1: per-(b,g,chunk) partial sum/sumsq ----------------
__global__ void gn_stats(const float* __restrict__ x, float* __restrict__ part) {
  int bx = blockIdx.x;            // 256 = bg(32) * chunk(8)
  int ch = bx & 7, bg = bx >> 3;
  const float* base = x + (size_t)bg * GROUP_ELEMS + (size_t)ch * 8192;
  int t = threadIdx.x;
  float s = 0.f, ss = 0.f;
  #pragma unroll
  for (int i = 0; i < 8; ++i) {
    float4 v = *(const float4*)(base + i * 1024 + t * 4);
    s  += v.x + v.y + v.z + v.w;
    ss += v.x * v.x + v.y * v.y + v.z * v.z + v.w * v.w;
  }
  #pragma unroll
  for (int off = 1; off < 64; off <<= 1) {
    s  += __shfl_xor(s, off);
    ss += __shfl_xor(ss, off);
  }
  __shared__ float red[8];
  int w = t >> 6;
  if ((t & 63) == 0) { red[w * 2] = s; red[w * 2 + 1] = ss; }
  __syncthreads();
  if (t == 0) {
    part[bx * 2]     = red[0] + red[2] + red[4] + red[6];
    part[bx * 2 + 1] = red[1] + red[3] + red[5] + red[7];
  }
}

// ---------------- GroupNorm pass 2: reduce partials, normalize, write xn (b,n,c) bf16 ----------------
__global__ void gn_apply(const float* __restrict__ x, const float* __restrict__ gw,
                         const float* __restrict__ gb, const float* __restrict__ part,
                         short* __restrict__ xn) {
  int bx = blockIdx.x;            // 256 = b(4) g(8) ns(8)
  int ns = bx & 7, g = (bx >> 3) & 7, b = bx >> 6;
  int bg = b * NGRP + g;
  float s = 0.f, ss = 0.f;
  #pragma unroll
  for (int j = 0; j < 8; ++j) {
    s  += part[(bg * 8 + j) * 2];
    ss += part[(bg * 8 + j) * 2 + 1];
  }
  float mean = s * (1.f / GROUP_ELEMS);
  float var  = ss * (1.f / GROUP_ELEMS) - mean * mean;
  float inv  = rsqrtf(var + EPS_GN);
  int t = threadIdx.x;
  int cl = t & 15, n4 = t >> 4;
  int c = g * 16 + cl;
  float ga = gw[c] * inv;
  float be = gb[c] - mean * ga;
  const float* xr = x + (size_t)(b * CCH + c) * NSP;
  short* xo = xn + (size_t)b * NSP * CCH + c;
  #pragma unroll
  for (int i = 0; i < 8; ++i) {
    int n = ns * 512 + i * 64 + n4 * 4;
    float4 v = *(const float4*)(xr + n);
    xo[(size_t)(n + 0) * CCH] = f2bf(v.x * ga + be);
    xo[(size_t)(n + 1) * CCH] = f2bf(v.y * ga + be);
    xo[(size_t)(n + 2) * CCH] = f2bf(v.z * ga + be);
    xo[(size_t)(n + 3) * CCH] = f2bf(v.w * ga + be);
  }
}

// ---------------- QKV (q,k part): D[n][o]; q pre-scaled by QSCALE ----------------
__global__ void qk_gemm(const short* __restrict__ xn, const float* __restrict__ Wqkv,
                        const float* __restrict__ bias, short* __restrict__ q,
                        short* __restrict__ k) {
  int bx = blockIdx.x;            // 1024 = b(4) nt(64) ot(4)
  int ot = bx & 3, nt = (bx >> 2) & 63, b = bx >> 8;
  __shared__ short Xl[64][136];
  __shared__ short Wl[64][136];
  int t = threadIdx.x;
  for (int idx = t; idx < 64 * 16; idx += 256) {
    int row = idx >> 4, c8 = idx & 15;
    *(s8b*)&Xl[row][c8 * 8] =
        *(const s8b*)(xn + ((size_t)(b * NSP + nt * 64 + row)) * CCH + c8 * 8);
  }
  for (int idx = t; idx < 64 * 16; idx += 256) {
    int row = idx >> 4, c8 = idx & 15;
    const float* src = Wqkv + (size_t)(ot * 64 + row) * CCH + c8 * 8;
    s8b wv;
    #pragma unroll
    for (int j = 0; j < 8; ++j) wv[j] = f2bf(src[j]);
    *(s8b*)&Wl[row][c8 * 8] = wv;
  }
  __syncthreads();
  int lane = t & 63, w = t >> 6, l15 = lane & 15, quad = lane >> 4;
  s8b a[4];
  #pragma unroll
  for (int kc = 0; kc < 4; ++kc) a[kc] = *(const s8b*)&Xl[w * 16 + l15][kc * 32 + quad * 8];
  #pragma unroll
  for (int o4 = 0; o4 < 4; ++o4) {
    f32x4 acc = {0.f, 0.f, 0.f, 0.f};
    #pragma unroll
    for (int kc = 0; kc < 4; ++kc) {
      s8b bw = *(const s8b*)&Wl[o4 * 16 + l15][kc * 32 + quad * 8];
      acc = mfma16(a[kc], bw, acc);
    }
    int obase = ot * 64 + o4 * 16;
    short* dst = (obase < 128) ? q : k;
    float mulf = (obase < 128) ? QSCALE : 1.0f;
    int oc = obase - ((obase < 128) ? 0 : 128) + l15;
    float bs = bias[obase + l15];
    #pragma unroll
    for (int r = 0; r < 4; ++r) {
      int n = nt * 64 + w * 16 + quad * 4 + r;
      dst[((size_t)(b * NSP + n)) * CCH + oc] = f2bf((acc[r] + bs) * mulf);
    }
  }
}

// ---------------- QKV (v part): D[o][n], writes v transposed (b,c,n) bf16 ----------------
__global__ void v_gemm(const short* __restrict__ xn, const float* __restrict__ Wqkv,
                       const float* __restrict__ bias, short* __restrict__ vt) {
  int bx = blockIdx.x;            // 256 = b(4) nt(32) ot(2)
  int ot = bx & 1, nt = (bx >> 1) & 31, b = bx >> 6;
  __shared__ short Xl[128][136];
  __shared__ short Wl[64][136];
  int t = threadIdx.x;
  for (int idx = t; idx < 128 * 16; idx += 256) {
    int row = idx >> 4, c8 = idx & 15;
    *(s8b*)&Xl[row][c8 * 8] =
        *(const s8b*)(xn + ((size_t)(b * NSP + nt * 128 + row)) * CCH + c8 * 8);
  }
  for (int idx = t; idx < 64 * 16; idx += 256) {
    int row = idx >> 4, c8 = idx & 15;
    const float* src = Wqkv + (size_t)(256 + ot * 64 + row) * CCH + c8 * 8;
    s8b wv;
    #pragma unroll
    for (int j = 0; j < 8; ++j) wv[j] = f2bf(src[j]);
    *(s8b*)&Wl[row][c8 * 8] = wv;
  }
  __syncthreads();
  int lane = t & 63, w = t >> 6, l15 = lane & 15, quad = lane >> 4;
  s8b a[4];
  #pragma unroll
  for (int kc = 0; kc < 4; ++kc) a[kc] = *(const s8b*)&Wl[w * 16 + l15][kc * 32 + quad * 8];
  float bs[4];
  #pragma unroll
  for (int r = 0; r < 4; ++r) bs[r] = bias[256 + ot * 64 + w * 16 + quad * 4 + r];
  #pragma unroll
  for (int ntile = 0; ntile < 8; ++ntile) {
    f32x4 acc = {0.f, 0.f, 0.f, 0.f};
    #pragma unroll
    for (int kc = 0; kc < 4; ++kc) {
      s8b bx2 = *(const s8b*)&Xl[ntile * 16 + l15][kc * 32 + quad * 8];
      acc = mfma16(a[kc], bx2, acc);
    }
    #pragma unroll
    for (int r = 0; r < 4; ++r) {
      int og = ot * 64 + w * 16 + quad * 4 + r;       // v channel
      int n = nt * 128 + ntile * 16 + l15;
      vt[((size_t)(b * CCH + og)) * NSP + n] = f2bf(acc[r] + bs[r]);
    }
  }
}

// ---------------- Flash attention v5.1: LDS-staged, async DMA, cross-block split-K ----------------
// Grid 512 = qt(32: 128-row tiles) x b(4) x kh(4 key quarters); bx%8 XCD-swizzle
// puts each (b,kh)'s 1MB K/V working set in one XCD's L2.
// Block 256 thr = 4 waves x 32 q-rows (Q resident, mt=2 reuses K-frags).
// K/V tiles (64 keys) staged double-buffered via global_load_lds with XOR
// source swizzle (dest must stay lane-contiguous) -> conflict-free b128 reads.
// Fixed-max softmax: partials are plain sums; bf16 partial O + fp32 partial l
// written per kh, merged for free inside proj_gemm.
// R5 FIX: STAGE macro's inner loop variable shadowed the K-loop's `i` that
// appeared in the key0 argument -> prefetch staged the wrong tiles. key0 is
// now evaluated into a local BEFORE the staging loop (and loop var renamed).
__global__ __launch_bounds__(256, 2) void flash(const short* __restrict__ q,
                                                const short* __restrict__ k,
                                                const short* __restrict__ vt,
                                                short* __restrict__ Op,
                                                float* __restrict__ Lp) {
  int bx = blockIdx.x;
  int kh = bx & 3, b = (bx >> 2) & 3, qt = bx >> 4;
  __shared__ short Kl[2][64 * 128];   // [key][ch], groups XOR-swizzled by (key&15)
  __shared__ short Vl[2][128 * 64];   // [ch][key], groups XOR-swizzled by (ch&7)
  __shared__ short Pl[4][16 * 74];    // per-wave P transpose
  int t = threadIdx.x;
  int lane = t & 63, w = t >> 6;
  int l15 = lane & 15, quad = lane >> 4;
  const short* kbase = k + (size_t)b * NSP * CCH;
  const short* vbase = vt + (size_t)b * CCH * NSP;
  int kt0 = kh * 1024;

  // staging source lane-coords (loop-invariant)
  int krow_in_chunk = lane >> 4, kgrp = lane & 15;
  int vrow_in_chunk = lane >> 3, vgrp = lane & 7;

  // Q A-fragments, resident: rows qt*128 + w*32 + mt*16 + l15
  s8b aq[2][4];
  #pragma unroll
  for (int mt = 0; mt < 2; ++mt) {
    const short* qp =
        q + ((size_t)(b * NSP + qt * 128 + w * 32 + mt * 16 + l15)) * CCH + quad * 8;
    #pragma unroll
    for (int kc = 0; kc < 4; ++kc) aq[mt][kc] = *(const s8b*)(qp + kc * 32);
  }
  f32x4 O[2][8];
  float l4[2][4];
  #pragma unroll
  for (int mt = 0; mt < 2; ++mt) {
    #pragma unroll
    for (int cg = 0; cg < 8; ++cg) O[mt][cg] = (f32x4){0.f, 0.f, 0.f, 0.f};
    #pragma unroll
    for (int r = 0; r < 4; ++r) l4[mt][r] = 0.f;
  }
  short* pw = &Pl[w][0];

  // stage one 64-key tile (K 16KB + V 16KB) into buf; 8 DMA instrs per wave.
  // key0_ is evaluated ONCE into key0v before the loop (macro-capture fix).
  #define STAGE(buf_, key0_)                                                        \
    {                                                                               \
      const int key0v = (key0_);                                                    \
      _Pragma("unroll") for (int si = 0; si < 4; ++si) {                            \
        int c = w * 4 + si;                                                         \
        int rt = c * 4 + krow_in_chunk;                                             \
        async16(kbase + (size_t)(key0v + rt) * CCH + ((kgrp ^ (rt & 15)) * 8),      \
                &Kl[buf_][c * 512]);                                                \
        int rc = c * 8 + vrow_in_chunk;                                             \
        async16(vbase + (size_t)rc * NSP + key0v + ((vgrp ^ (rc & 7)) * 8),         \
                &Vl[buf_][c * 512]);                                                \
      }                                                                             \
    }

  STAGE(0, kt0)
  __syncthreads();

  for (int i = 0; i < 16; ++i) {
    int buf = i & 1;
    if (i < 15) STAGE(buf ^ 1, kt0 + (i + 1) * 64)

    // ---- S = Q K^T : 32 q-rows x 64 keys ----
    f32x4 s[2][4];
    #pragma unroll
    for (int g2 = 0; g2 < 4; ++g2) {
      const short* kp = &Kl[buf][(g2 * 16 + l15) * 128];
      s8b bk[4];
      #pragma unroll
      for (int kc = 0; kc < 4; ++kc)
        bk[kc] = *(const s8b*)&kp[((kc * 4 + quad) ^ l15) * 8];
      #pragma unroll
      for (int mt = 0; mt < 2; ++mt) {
        f32x4 acc = {0.f, 0.f, 0.f, 0.f};
        acc = mfma16(aq[mt][0], bk[0], acc);
        acc = mfma16(aq[mt][1], bk[1], acc);
        acc = mfma16(aq[mt][2], bk[2], acc);
        acc = mfma16(aq[mt][3], bk[3], acc);
        s[mt][g2] = acc;
      }
    }
    // ---- V B-fragments (shared across both m-tiles) ----
    s8b vf[8][2];
    #pragma unroll
    for (int cg = 0; cg < 8; ++cg) {
      const short* vp = &Vl[buf][(cg * 16 + l15) * 64];
      vf[cg][0] = *(const s8b*)&vp[((quad) ^ (l15 & 7)) * 8];
      vf[cg][1] = *(const s8b*)&vp[((4 + quad) ^ (l15 & 7)) * 8];
    }
    // ---- per m-tile: p=exp2(s), pack via LDS, PV ----
    #pragma unroll
    for (int mt = 0; mt < 2; ++mt) {
      #pragma unroll
      for (int g2 = 0; g2 < 4; ++g2) {
        #pragma unroll
        for (int r = 0; r < 4; ++r) {
          float p = fexp2(s[mt][g2][r]);
          l4[mt][r] += p;
          unsigned u; __builtin_memcpy(&u, &p, 4);
          pw[(quad * 4 + r) * 74 + g2 * 16 + l15] = (short)((u + 0x8000u) >> 16);
        }
      }
      s8b pf0 = *(const s8b*)&pw[l15 * 74 + quad * 8];
      s8b pf1 = *(const s8b*)&pw[l15 * 74 + 32 + quad * 8];
      #pragma unroll
      for (int cg = 0; cg < 8; ++cg) {
        O[mt][cg] = mfma16(pf0, vf[cg][0], O[mt][cg]);
        O[mt][cg] = mfma16(pf1, vf[cg][1], O[mt][cg]);
      }
    }
    __syncthreads();
  }

  // ---- deferred l reduction (across the 16 column-lanes) ----
  #pragma unroll
  for (int off = 1; off < 16; off <<= 1)
    #pragma unroll
    for (int mt = 0; mt < 2; ++mt)
      #pragma unroll
      for (int r = 0; r < 4; ++r) l4[mt][r] += __shfl_xor(l4[mt][r], off);

  // ---- write bf16 partial O + fp32 partial l for this kh ----
  short* ob = Op + (size_t)kh * OPSTRIDE + ((size_t)(b * NSP + qt * 128)) * CCH;
  float* lp = Lp + kh * LPSTRIDE + b * NSP + qt * 128;
  #pragma unroll
  for (int mt = 0; mt < 2; ++mt) {
    #pragma unroll
    for (int r = 0; r < 4; ++r) {
      int n = w * 32 + mt * 16 + quad * 4 + r;
      if (l15 == 0) lp[n] = l4[mt][r];
      #pragma unroll
      for (int cg = 0; cg < 8; ++cg)
        ob[(size_t)n * CCH + cg * 16 + l15] = f2bf(O[mt][cg][r]);
    }
  }
}

// ---------------- proj + bias + residual, merging the 4 kh partials ----------------
__global__ void proj_gemm(const short* __restrict__ Op, const float* __restrict__ Lp,
                          const float* __restrict__ Wp, const float* __restrict__ pbias,
                          const float* __restrict__ x, float* __restrict__ out) {
  int bx = blockIdx.x;            // 256 = b(4) nt(64)
  int nt = bx & 63, b = bx >> 6;
  __shared__ short Wl[128][136];
  int t = threadIdx.x;
  for (int idx = t; idx < 128 * 16; idx += 256) {
    int row = idx >> 4, c8 = idx & 15;
    const float* src = Wp + (size_t)row * CCH + c8 * 8;
    s8b wv;
    #pragma unroll
    for (int j = 0; j < 8; ++j) wv[j] = f2bf(src[j]);
    *(s8b*)&Wl[row][c8 * 8] = wv;
  }
  __syncthreads();
  int lane = t & 63, w = t >> 6, l15 = lane & 15, quad = lane >> 4;
  int row = nt * 64 + w * 16 + l15;             // this lane's ao row (m index)
  float lsum = Lp[0 * LPSTRIDE + b * NSP + row] + Lp[1 * LPSTRIDE + b * NSP + row] +
               Lp[2 * LPSTRIDE + b * NSP + row] + Lp[3 * LPSTRIDE + b * NSP + row];
  float linv = 1.f / lsum;
  const short* ap = Op + ((size_t)(b * NSP + row)) * CCH + quad * 8;
  s8b bfr[4];
  #pragma unroll
  for (int kc = 0; kc < 4; ++kc) {
    float acc8[8];
    #pragma unroll
    for (int j = 0; j < 8; ++j) acc8[j] = 0.f;
    #pragma unroll
    for (int s = 0; s < 4; ++s) {
      s8b tv = *(const s8b*)(ap + (size_t)s * OPSTRIDE + kc * 32);
      #pragma unroll
      for (int j = 0; j < 8; ++j) acc8[j] += bf2f(tv[j]);
    }
    #pragma unroll
    for (int j = 0; j < 8; ++j) bfr[kc][j] = f2bf(acc8[j] * linv);
  }
  #pragma unroll
  for (int cg = 0; cg < 8; ++cg) {
    f32x4 acc = {0.f, 0.f, 0.f, 0.f};
    #pragma unroll
    for (int kc = 0; kc < 4; ++kc) {
      s8b aw = *(const s8b*)&Wl[cg * 16 + l15][kc * 32 + quad * 8];
      acc = mfma16(aw, bfr[kc], acc);
    }
    #pragma unroll
    for (int r = 0; r < 4; ++r) {
      int co = cg * 16 + quad * 4 + r;
      int n = nt * 64 + w * 16 + l15;
      size_t off = ((size_t)(b * CCH + co)) * NSP + n;
      out[off] = x[off] + acc[r] + pbias[co];
    }
  }
}

extern "C" void kernel_launch(void* const* d_in, const int* in_sizes, int n_in,
                              void* d_out, int out_size, void* d_ws, size_t ws_size,
                              hipStream_t stream) {
  (void)in_sizes; (void)n_in; (void)out_size; (void)ws_size;
  const float* x    = (const float*)d_in[0];
  const float* gw   = (const float*)d_in[1];
  const float* gb   = (const float*)d_in[2];
  const float* Wqkv = (const float*)d_in[3];
  const float* bqkv = (const float*)d_in[4];
  const float* Wp   = (const float*)d_in[5];
  const float* bp   = (const float*)d_in[6];
  float* out = (float*)d_out;
  char* ws = (char*)d_ws;
  float* part = (float*)ws;                             // 512 floats
  short* xn    = (short*)(ws + 4096);
  short* q     = (short*)(ws + 4096 + 1ull * 4194304);
  short* k     = (short*)(ws + 4096 + 2ull * 4194304);
  short* vt    = (short*)(ws + 4096 + 3ull * 4194304);
  short* Opart = (short*)(ws + 4096 + 4ull * 4194304);  // 4 x 4MB bf16 partial O
  float* Lpart = (float*)(ws + 4096 + 8ull * 4194304);  // 4 x 64KB fp32 partial l

  gn_stats<<<256, 256, 0, stream>>>(x, part);
  gn_apply<<<256, 256, 0, stream>>>(x, gw, gb, part, xn);
  qk_gemm<<<1024, 256, 0, stream>>>(xn, Wqkv, bqkv, q, k);
  v_gemm<<<256, 256, 0, stream>>>(xn, Wqkv, bqkv, vt);
  flash<<<512, 256, 0, stream>>>(q, k, vt, Opart, Lpart);
  proj_gemm<<<256, 256, 0, stream>>>(Opart, Lpart, Wp, bp, x, out);
}

// Round 6
// 135.611 us; speedup vs baseline: 2.3983x; 1.1043x over previous
//
#include <hip/hip_runtime.h>

#define BATCH 4
#define CCH 128
#define NSP 4096
#define NGRP 8
#define GROUP_ELEMS 65536   // 16 ch * 4096
// ATT_SCALE * log2(e): folded into q at qkv_gemm so softmax is exp2(s)
#define QSCALE 0.12751744f
#define EPS_GN 1e-5f
#define OPSTRIDE 2097152    // 4*4096*128 shorts per kh partial
#define LPSTRIDE 16384      // 4*4096 floats per kh partial

typedef short s8b __attribute__((ext_vector_type(8)));
typedef float f32x4 __attribute__((ext_vector_type(4)));

static __device__ __forceinline__ short f2bf(float f) {
  union { float f; unsigned u; } v; v.f = f;
  unsigned r = (v.u + 0x7FFFu + ((v.u >> 16) & 1u)) >> 16;
  return (short)r;
}

static __device__ __forceinline__ float bf2f(short s) {
  unsigned u = ((unsigned)(unsigned short)s) << 16;
  float f; __builtin_memcpy(&f, &u, 4); return f;
}

static __device__ __forceinline__ float fexp2(float x) {
#if __has_builtin(__builtin_amdgcn_exp2f)
  return __builtin_amdgcn_exp2f(x);
#else
  return exp2f(x);
#endif
}

// pack two floats to adjacent bf16 (round-half-up) in one u32: lo=a, hi=b
static __device__ __forceinline__ unsigned pack2bf(float a, float b) {
  unsigned ua, ub;
  __builtin_memcpy(&ua, &a, 4); __builtin_memcpy(&ub, &b, 4);
  ua += 0x8000u; ub += 0x8000u;
#if __has_builtin(__builtin_amdgcn_perm)
  return __builtin_amdgcn_perm(ub, ua, 0x07060302u);  // bytes: ua[3:2] | ub[3:2]
#else
  return (ua >> 16) | (ub & 0xFFFF0000u);
#endif
}

static __device__ __forceinline__ f32x4 mfma16(s8b a, s8b b, f32x4 c) {
  return __builtin_amdgcn_mfma_f32_16x16x32_bf16(a, b, c, 0, 0, 0);
}

// async 16B global->LDS DMA; dest = wave-uniform base + lane*16
static __device__ __forceinline__ void async16(const void* g, void* l) {
  __builtin_amdgcn_global_load_lds(
      (const __attribute__((address_space(1))) void*)g,
      (__attribute__((address_space(3))) void*)l, 16, 0, 0);
}

// ---------------- GroupNorm pass 1: per-(b,g,chunk) partial sum/sumsq ----------------
__global__ void gn_stats(const float* __restrict__ x, float* __restrict__ part) {
  int bx = blockIdx.x;            // 256 = bg(32) * chunk(8)
  int ch = bx & 7, bg = bx >> 3;
  const float* base = x + (size_t)bg * GROUP_ELEMS + (size_t)ch * 8192;
  int t = threadIdx.x;
  float s = 0.f, ss = 0.f;
  #pragma unroll
  for (int i = 0; i < 8; ++i) {
    float4 v = *(const float4*)(base + i * 1024 + t * 4);
    s  += v.x + v.y + v.z + v.w;
    ss += v.x * v.x + v.y * v.y + v.z * v.z + v.w * v.w;
  }
  #pragma unroll
  for (int off = 1; off < 64; off <<= 1) {
    s  += __shfl_xor(s, off);
    ss += __shfl_xor(ss, off);
  }
  __shared__ float red[8];
  int w = t >> 6;
  if ((t & 63) == 0) { red[w * 2] = s; red[w * 2 + 1] = ss; }
  __syncthreads();
  if (t == 0) {
    part[bx * 2]     = red[0] + red[2] + red[4] + red[6];
    part[bx * 2 + 1] = red[1] + red[3] + red[5] + red[7];
  }
}

// ---------------- GroupNorm pass 2: reduce partials, normalize, write xn (b,n,c) bf16 ----------------
__global__ void gn_apply(const float* __restrict__ x, const float* __restrict__ gw,
                         const float* __restrict__ gb, const float* __restrict__ part,
                         short* __restrict__ xn) {
  int bx = blockIdx.x;            // 256 = b(4) g(8) ns(8)
  int ns = bx & 7, g = (bx >> 3) & 7, b = bx >> 6;
  int bg = b * NGRP + g;
  float s = 0.f, ss = 0.f;
  #pragma unroll
  for (int j = 0; j < 8; ++j) {
    s  += part[(bg * 8 + j) * 2];
    ss += part[(bg * 8 + j) * 2 + 1];
  }
  float mean = s * (1.f / GROUP_ELEMS);
  float var  = ss * (1.f / GROUP_ELEMS) - mean * mean;
  float inv  = rsqrtf(var + EPS_GN);
  int t = threadIdx.x;
  int cl = t & 15, n4 = t >> 4;
  int c = g * 16 + cl;
  float ga = gw[c] * inv;
  float be = gb[c] - mean * ga;
  const float* xr = x + (size_t)(b * CCH + c) * NSP;
  short* xo = xn + (size_t)b * NSP * CCH + c;
  #pragma unroll
  for (int i = 0; i < 8; ++i) {
    int n = ns * 512 + i * 64 + n4 * 4;
    float4 v = *(const float4*)(xr + n);
    xo[(size_t)(n + 0) * CCH] = f2bf(v.x * ga + be);
    xo[(size_t)(n + 1) * CCH] = f2bf(v.y * ga + be);
    xo[(size_t)(n + 2) * CCH] = f2bf(v.z * ga + be);
    xo[(size_t)(n + 3) * CCH] = f2bf(v.w * ga + be);
  }
}

// ---------------- Fused QKV: bx<1024 -> q,k (D[n][o]); else -> v (D[o][n], permuted key order) ----------------
// v is written TRANSPOSED (b,c,n) with each 64-key group's key order permuted:
// orig key o = g2*16+l15  ->  pos = l15*2 + (g2&1) + 32*(g2>>1)
// so flash's P-pack can emit LDS-adjacent bf16 pairs. PV is key-order invariant.
__global__ void qkv_gemm(const short* __restrict__ xn, const float* __restrict__ Wqkv,
                         const float* __restrict__ bias, short* __restrict__ q,
                         short* __restrict__ k, short* __restrict__ vt) {
  __shared__ short Xl[128 * 136];
  __shared__ short Wl[64 * 136];
  int bx = blockIdx.x;
  int t = threadIdx.x;
  int lane = t & 63, w = t >> 6, l15 = lane & 15, quad = lane >> 4;
  if (bx < 1024) {
    // ---------- q,k part ----------
    int ot = bx & 3, nt = (bx >> 2) & 63, b = bx >> 8;
    for (int idx = t; idx < 64 * 16; idx += 256) {
      int row = idx >> 4, c8 = idx & 15;
      *(s8b*)&Xl[row * 136 + c8 * 8] =
          *(const s8b*)(xn + ((size_t)(b * NSP + nt * 64 + row)) * CCH + c8 * 8);
    }
    for (int idx = t; idx < 64 * 16; idx += 256) {
      int row = idx >> 4, c8 = idx & 15;
      const float* src = Wqkv + (size_t)(ot * 64 + row) * CCH + c8 * 8;
      s8b wv;
      #pragma unroll
      for (int j = 0; j < 8; ++j) wv[j] = f2bf(src[j]);
      *(s8b*)&Wl[row * 136 + c8 * 8] = wv;
    }
    __syncthreads();
    s8b a[4];
    #pragma unroll
    for (int kc = 0; kc < 4; ++kc)
      a[kc] = *(const s8b*)&Xl[(w * 16 + l15) * 136 + kc * 32 + quad * 8];
    #pragma unroll
    for (int o4 = 0; o4 < 4; ++o4) {
      f32x4 acc = {0.f, 0.f, 0.f, 0.f};
      #pragma unroll
      for (int kc = 0; kc < 4; ++kc) {
        s8b bw = *(const s8b*)&Wl[(o4 * 16 + l15) * 136 + kc * 32 + quad * 8];
        acc = mfma16(a[kc], bw, acc);
      }
      int obase = ot * 64 + o4 * 16;
      short* dst = (obase < 128) ? q : k;
      float mulf = (obase < 128) ? QSCALE : 1.0f;
      int oc = obase - ((obase < 128) ? 0 : 128) + l15;
      float bs = bias[obase + l15];
      #pragma unroll
      for (int r = 0; r < 4; ++r) {
        int n = nt * 64 + w * 16 + quad * 4 + r;
        dst[((size_t)(b * NSP + n)) * CCH + oc] = f2bf((acc[r] + bs) * mulf);
      }
    }
  } else {
    // ---------- v part ----------
    int vbx = bx - 1024;            // 256 = b(4) nt(32) ot(2)
    int ot = vbx & 1, nt = (vbx >> 1) & 31, b = vbx >> 6;
    for (int idx = t; idx < 128 * 16; idx += 256) {
      int row = idx >> 4, c8 = idx & 15;
      *(s8b*)&Xl[row * 136 + c8 * 8] =
          *(const s8b*)(xn + ((size_t)(b * NSP + nt * 128 + row)) * CCH + c8 * 8);
    }
    for (int idx = t; idx < 64 * 16; idx += 256) {
      int row = idx >> 4, c8 = idx & 15;
      const float* src = Wqkv + (size_t)(256 + ot * 64 + row) * CCH + c8 * 8;
      s8b wv;
      #pragma unroll
      for (int j = 0; j < 8; ++j) wv[j] = f2bf(src[j]);
      *(s8b*)&Wl[row * 136 + c8 * 8] = wv;
    }
    __syncthreads();
    s8b a[4];
    #pragma unroll
    for (int kc = 0; kc < 4; ++kc)
      a[kc] = *(const s8b*)&Wl[(w * 16 + l15) * 136 + kc * 32 + quad * 8];
    float bs[4];
    #pragma unroll
    for (int r = 0; r < 4; ++r) bs[r] = bias[256 + ot * 64 + w * 16 + quad * 4 + r];
    #pragma unroll
    for (int ntile = 0; ntile < 8; ++ntile) {
      f32x4 acc = {0.f, 0.f, 0.f, 0.f};
      #pragma unroll
      for (int kc = 0; kc < 4; ++kc) {
        s8b bx2 = *(const s8b*)&Xl[(ntile * 16 + l15) * 136 + kc * 32 + quad * 8];
        acc = mfma16(a[kc], bx2, acc);
      }
      int g2 = ntile & 3;
      int npos = nt * 128 + (ntile >> 2) * 64 + l15 * 2 + (g2 & 1) + 32 * (g2 >> 1);
      #pragma unroll
      for (int r = 0; r < 4; ++r) {
        int og = ot * 64 + w * 16 + quad * 4 + r;     // v channel
        vt[((size_t)(b * CCH + og)) * NSP + npos] = f2bf(acc[r] + bs[r]);
      }
    }
  }
}

// ---------------- Flash attention v6 ----------------
// Grid 512 = qt(32: 128-row tiles) x b(4) x kh(4 key quarters).
// Block 256 thr = 4 waves x 32 q-rows (Q resident, mt=2 reuses K-frags).
// K/V double-buffered via global_load_lds, XOR source swizzle.
// Softmax: fixed max=0, p=exp2(s); row-sum l computed BY MFMA with a ones
// B-operand (lands per-lane exactly where the old butterfly put it).
// P pack: paired bf16 (v_perm_b32) + ds_write_b32, enabled by v's permuted
// key order. Partial O (bf16) + l (fp32) per kh; merged inside proj_gemm.
__global__ __launch_bounds__(256, 2) void flash(const short* __restrict__ q,
                                                const short* __restrict__ k,
                                                const short* __restrict__ vt,
                                                short* __restrict__ Op,
                                                float* __restrict__ Lp) {
  int bx = blockIdx.x;
  int kh = bx & 3, b = (bx >> 2) & 3, qt = bx >> 4;
  __shared__ short Kl[2][64 * 128];   // [key][ch], 8-short groups XOR-swizzled by (key&15)
  __shared__ short Vl[2][128 * 64];   // [ch][pos], 8-short groups XOR-swizzled by (ch&7)
  __shared__ short Pl[4][16 * 72];    // per-wave P transpose, pitch 72
  int t = threadIdx.x;
  int lane = t & 63, w = t >> 6;
  int l15 = lane & 15, quad = lane >> 4;
  const short* kbase = k + (size_t)b * NSP * CCH;
  const short* vbase = vt + (size_t)b * CCH * NSP;
  int kt0 = kh * 1024;

  int krow_in_chunk = lane >> 4, kgrp = lane & 15;
  int vrow_in_chunk = lane >> 3, vgrp = lane & 7;

  s8b aq[2][4];
  #pragma unroll
  for (int mt = 0; mt < 2; ++mt) {
    const short* qp =
        q + ((size_t)(b * NSP + qt * 128 + w * 32 + mt * 16 + l15)) * CCH + quad * 8;
    #pragma unroll
    for (int kc = 0; kc < 4; ++kc) aq[mt][kc] = *(const s8b*)(qp + kc * 32);
  }
  f32x4 O[2][8];
  f32x4 L[2];
  #pragma unroll
  for (int mt = 0; mt < 2; ++mt) {
    #pragma unroll
    for (int cg = 0; cg < 8; ++cg) O[mt][cg] = (f32x4){0.f, 0.f, 0.f, 0.f};
    L[mt] = (f32x4){0.f, 0.f, 0.f, 0.f};
  }
  s8b vone;
  #pragma unroll
  for (int j = 0; j < 8; ++j) vone[j] = (short)0x3F80;   // bf16 1.0
  short* pw = &Pl[w][0];

  #define STAGE(buf_, key0_)                                                        \
    {                                                                               \
      const int key0v = (key0_);                                                    \
      _Pragma("unroll") for (int si = 0; si < 4; ++si) {                            \
        int c = w * 4 + si;                                                         \
        int rt = c * 4 + krow_in_chunk;                                             \
        async16(kbase + (size_t)(key0v + rt) * CCH + ((kgrp ^ (rt & 15)) * 8),      \
                &Kl[buf_][c * 512]);                                                \
        int rc = c * 8 + vrow_in_chunk;                                             \
        async16(vbase + (size_t)rc * NSP + key0v + ((vgrp ^ (rc & 7)) * 8),         \
                &Vl[buf_][c * 512]);                                                \
      }                                                                             \
    }

  STAGE(0, kt0)
  __syncthreads();

  for (int i = 0; i < 16; ++i) {
    int buf = i & 1;
    if (i < 15) STAGE(buf ^ 1, kt0 + (i + 1) * 64)

    // ---- S = Q K^T : 32 q-rows x 64 keys ----
    f32x4 s[2][4];
    #pragma unroll
    for (int g2 = 0; g2 < 4; ++g2) {
      const short* kp = &Kl[buf][(g2 * 16 + l15) * 128];
      s8b bk[4];
      #pragma unroll
      for (int kc = 0; kc < 4; ++kc)
        bk[kc] = *(const s8b*)&kp[((kc * 4 + quad) ^ l15) * 8];
      #pragma unroll
      for (int mt = 0; mt < 2; ++mt) {
        f32x4 acc = {0.f, 0.f, 0.f, 0.f};
        acc = mfma16(aq[mt][0], bk[0], acc);
        acc = mfma16(aq[mt][1], bk[1], acc);
        acc = mfma16(aq[mt][2], bk[2], acc);
        acc = mfma16(aq[mt][3], bk[3], acc);
        s[mt][g2] = acc;
      }
    }
    // ---- V B-fragments ----
    s8b vf[8][2];
    #pragma unroll
    for (int cg = 0; cg < 8; ++cg) {
      const short* vp = &Vl[buf][(cg * 16 + l15) * 64];
      vf[cg][0] = *(const s8b*)&vp[((quad) ^ (l15 & 7)) * 8];
      vf[cg][1] = *(const s8b*)&vp[((4 + quad) ^ (l15 & 7)) * 8];
    }
    // ---- per m-tile: p=exp2(s), paired pack -> LDS, PV + l-mfma ----
    #pragma unroll
    for (int mt = 0; mt < 2; ++mt) {
      #pragma unroll
      for (int r = 0; r < 4; ++r) {
        float p0 = fexp2(s[mt][0][r]);
        float p1 = fexp2(s[mt][1][r]);
        float p2 = fexp2(s[mt][2][r]);
        float p3 = fexp2(s[mt][3][r]);
        // col' = l15*2 + (g2&1) + 32*(g2>>1): (p0,p1) adjacent, (p2,p3) adjacent
        *(unsigned*)&pw[(quad * 4 + r) * 72 + l15 * 2]      = pack2bf(p0, p1);
        *(unsigned*)&pw[(quad * 4 + r) * 72 + 32 + l15 * 2] = pack2bf(p2, p3);
      }
      s8b pf0 = *(const s8b*)&pw[l15 * 72 + quad * 8];
      s8b pf1 = *(const s8b*)&pw[l15 * 72 + 32 + quad * 8];
      L[mt] = mfma16(pf0, vone, L[mt]);
      L[mt] = mfma16(pf1, vone, L[mt]);
      #pragma unroll
      for (int cg = 0; cg < 8; ++cg) {
        O[mt][cg] = mfma16(pf0, vf[cg][0], O[mt][cg]);
        O[mt][cg] = mfma16(pf1, vf[cg][1], O[mt][cg]);
      }
    }
    __syncthreads();
  }

  // ---- write bf16 partial O + fp32 partial l for this kh ----
  // L[mt][r] already holds the row-sum for q-row quad*4+r (uniform over l15).
  short* ob = Op + (size_t)kh * OPSTRIDE + ((size_t)(b * NSP + qt * 128)) * CCH;
  float* lp = Lp + kh * LPSTRIDE + b * NSP + qt * 128;
  #pragma unroll
  for (int mt = 0; mt < 2; ++mt) {
    #pragma unroll
    for (int r = 0; r < 4; ++r) {
      int n = w * 32 + mt * 16 + quad * 4 + r;
      if (l15 == 0) lp[n] = L[mt][r];
      #pragma unroll
      for (int cg = 0; cg < 8; ++cg)
        ob[(size_t)n * CCH + cg * 16 + l15] = f2bf(O[mt][cg][r]);
    }
  }
}

// ---------------- proj + bias + residual, merging the 4 kh partials ----------------
__global__ void proj_gemm(const short* __restrict__ Op, const float* __restrict__ Lp,
                          const float* __restrict__ Wp, const float* __restrict__ pbias,
                          const float* __restrict__ x, float* __restrict__ out) {
  int bx = blockIdx.x;            // 256 = b(4) nt(64)
  int nt = bx & 63, b = bx >> 6;
  __shared__ short Wl[128][136];
  int t = threadIdx.x;
  for (int idx = t; idx < 128 * 16; idx += 256) {
    int row = idx >> 4, c8 = idx & 15;
    const float* src = Wp + (size_t)row * CCH + c8 * 8;
    s8b wv;
    #pragma unroll
    for (int j = 0; j < 8; ++j) wv[j] = f2bf(src[j]);
    *(s8b*)&Wl[row][c8 * 8] = wv;
  }
  __syncthreads();
  int lane = t & 63, w = t >> 6, l15 = lane & 15, quad = lane >> 4;
  int row = nt * 64 + w * 16 + l15;             // this lane's ao row (m index)
  float lsum = Lp[0 * LPSTRIDE + b * NSP + row] + Lp[1 * LPSTRIDE + b * NSP + row] +
               Lp[2 * LPSTRIDE + b * NSP + row] + Lp[3 * LPSTRIDE + b * NSP + row];
  float linv = 1.f / lsum;
  const short* ap = Op + ((size_t)(b * NSP + row)) * CCH + quad * 8;
  s8b bfr[4];
  #pragma unroll
  for (int kc = 0; kc < 4; ++kc) {
    float acc8[8];
    #pragma unroll
    for (int j = 0; j < 8; ++j) acc8[j] = 0.f;
    #pragma unroll
    for (int s = 0; s < 4; ++s) {
      s8b tv = *(const s8b*)(ap + (size_t)s * OPSTRIDE + kc * 32);
      #pragma unroll
      for (int j = 0; j < 8; ++j) acc8[j] += bf2f(tv[j]);
    }
    #pragma unroll
    for (int j = 0; j < 8; ++j) bfr[kc][j] = f2bf(acc8[j] * linv);
  }
  #pragma unroll
  for (int cg = 0; cg < 8; ++cg) {
    f32x4 acc = {0.f, 0.f, 0.f, 0.f};
    #pragma unroll
    for (int kc = 0; kc < 4; ++kc) {
      s8b aw = *(const s8b*)&Wl[cg * 16 + l15][kc * 32 + quad * 8];
      acc = mfma16(aw, bfr[kc], acc);
    }
    #pragma unroll
    for (int r = 0; r < 4; ++r) {
      int co = cg * 16 + quad * 4 + r;
      int n = nt * 64 + w * 16 + l15;
      size_t off = ((size_t)(b * CCH + co)) * NSP + n;
      out[off] = x[off] + acc[r] + pbias[co];
    }
  }
}

extern "C" void kernel_launch(void* const* d_in, const int* in_sizes, int n_in,
                              void* d_out, int out_size, void* d_ws, size_t ws_size,
                              hipStream_t stream) {
  (void)in_sizes; (void)n_in; (void)out_size; (void)ws_size;
  const float* x    = (const float*)d_in[0];
  const float* gw   = (const float*)d_in[1];
  const float* gb   = (const float*)d_in[2];
  const float* Wqkv = (const float*)d_in[3];
  const float* bqkv = (const float*)d_in[4];
  const float* Wp   = (const float*)d_in[5];
  const float* bp   = (const float*)d_in[6];
  float* out = (float*)d_out;
  char* ws = (char*)d_ws;
  float* part = (float*)ws;                             // 512 floats
  short* xn    = (short*)(ws + 4096);
  short* q     = (short*)(ws + 4096 + 1ull * 4194304);
  short* k     = (short*)(ws + 4096 + 2ull * 4194304);
  short* vt    = (short*)(ws + 4096 + 3ull * 4194304);
  short* Opart = (short*)(ws + 4096 + 4ull * 4194304);  // 4 x 4MB bf16 partial O
  float* Lpart = (float*)(ws + 4096 + 8ull * 4194304);  // 4 x 64KB fp32 partial l

  gn_stats<<<256, 256, 0, stream>>>(x, part);
  gn_apply<<<256, 256, 0, stream>>>(x, gw, gb, part, xn);
  qkv_gemm<<<1280, 256, 0, stream>>>(xn, Wqkv, bqkv, q, k, vt);
  flash<<<512, 256, 0, stream>>>(q, k, vt, Opart, Lpart);
  proj_gemm<<<256, 256, 0, stream>>>(Opart, Lpart, Wp, bp, x, out);
}